// Round 7
// baseline (13865.140 us; speedup 1.0000x reference)
//
#include <hip/hip_runtime.h>

// Reservoir forward, R7: R6 + split-phase chunked poll/compute pipeline.
//   State exchange = epoch-tagged u64 (value|epoch) relaxed agent-scope atomics
//   resolving at the Infinity Cache. Per step, state is consumed in 2 chunks of
//   1024 rows: wait chunk0 -> stage -> sync -> FMA chunk0 (chunk1 polls in
//   flight) -> wait chunk1 -> stage -> sync -> FMA chunk1 -> reduce/publish.
//   Overlaps ~half the compute with the cross-chip observe latency.

typedef unsigned long long u64;

#define NRES 2048
#define NIN  64
#define NOUT 16
#define TT   4096
#define GWG  128           // workgroups
#define BTH  512           // threads per wg (8 waves)
#define ROWS_PER_WG 16     // NRES / GWG, 2 rows per wave
#define NJ 8               // float4 blocks per lane (32 cols); 4 per chunk

__global__ void init_ws(u64* statebuf) {
    int i = blockIdx.x * blockDim.x + threadIdx.x;
    if (i < NRES)            statebuf[i] = 0ull;                   // buf0: epoch 0, value 0
    else if (i < 2 * NRES)   statebuf[i] = 0xFFFFFFFF00000000ull;  // buf1: invalid epoch
}

__launch_bounds__(BTH, 2)   // VGPR cap 256; W (64 regs) + pipeline state fits
__global__ void reservoir_run(const float* __restrict__ inputs,
                              const float* __restrict__ outputs,
                              const float* __restrict__ noise,
                              const float* __restrict__ w,
                              const float* __restrict__ w_in,
                              const float* __restrict__ w_feedb,
                              u64* statebuf)
{
    const int wg   = blockIdx.x;      // 0..127
    const int tid  = threadIdx.x;     // 0..511
    const int wave = tid >> 6;        // 0..7
    const int lane = tid & 63;
    const int row0 = wg * ROWS_PER_WG + wave * 2;   // wave owns rows row0, row0+1

    // ---- W rows into VGPRs: 2 rows x 8 float4 = 64 regs/thread ----
    const float4* wr0 = (const float4*)(w + (size_t)(row0 + 0) * NRES);
    const float4* wr1 = (const float4*)(w + (size_t)(row0 + 1) * NRES);
    float4 wv0[NJ], wv1[NJ];
#pragma unroll
    for (int j = 0; j < NJ; ++j) {
        wv0[j] = wr0[64 * j + lane];
        wv1[j] = wr1[64 * j + lane];
    }
    // pin: block rematerialization (R3's failure mode)
#pragma unroll
    for (int j = 0; j < NJ; ++j) {
        asm volatile("" : "+v"(wv0[j].x), "+v"(wv0[j].y), "+v"(wv0[j].z), "+v"(wv0[j].w));
        asm volatile("" : "+v"(wv1[j].x), "+v"(wv1[j].y), "+v"(wv1[j].z), "+v"(wv1[j].w));
    }
    const float wi0 = w_in[(row0 + 0) * NIN + lane];
    const float wi1 = w_in[(row0 + 1) * NIN + lane];
    const float wf0 = (lane < NOUT) ? w_feedb[(row0 + 0) * NOUT + lane] : 0.0f;
    const float wf1 = (lane < NOUT) ? w_feedb[(row0 + 1) * NOUT + lane] : 0.0f;

    __shared__ float s_state[2][NRES];   // 16 KB parity double buffer

    // software-pipelined externals
    float inp_c = inputs[1 * NIN + lane];
    float po_c  = (lane < NOUT) ? outputs[0 * NOUT + lane] : 0.0f;
    float nz_c  = (lane < 2) ? noise[(size_t)1 * NRES + row0 + lane] : 0.0f;

    for (int t = 1; t < TT; ++t) {
        const u64* sbuf = statebuf + ((t - 1) & 1) * NRES;
        u64*       dbuf = statebuf + (t & 1) * NRES;
        float*     sl   = s_state[(t - 1) & 1];
        const unsigned want = (unsigned)(t - 1);

        float a0 = fmaf(wf0, po_c, wi0 * inp_c);
        float a1 = fmaf(wf1, po_c, wi1 * inp_c);
        const float nz = nz_c;

        // ---- issue all 4 poll loads (in flight together) ----
        u64 p0 = __hip_atomic_load(&sbuf[tid],        __ATOMIC_RELAXED, __HIP_MEMORY_SCOPE_AGENT);
        u64 p1 = __hip_atomic_load(&sbuf[tid +  512], __ATOMIC_RELAXED, __HIP_MEMORY_SCOPE_AGENT);
        u64 p2 = __hip_atomic_load(&sbuf[tid + 1024], __ATOMIC_RELAXED, __HIP_MEMORY_SCOPE_AGENT);
        u64 p3 = __hip_atomic_load(&sbuf[tid + 1536], __ATOMIC_RELAXED, __HIP_MEMORY_SCOPE_AGENT);

        // ---- chunk-0 gate (rows 0..1023) ----
        while ((unsigned)(p0 >> 32) != want)
            p0 = __hip_atomic_load(&sbuf[tid],        __ATOMIC_RELAXED, __HIP_MEMORY_SCOPE_AGENT);
        while ((unsigned)(p1 >> 32) != want)
            p1 = __hip_atomic_load(&sbuf[tid +  512], __ATOMIC_RELAXED, __HIP_MEMORY_SCOPE_AGENT);

        // refresh chunk-1 polls now; results arrive during chunk-0 compute
        if ((unsigned)(p2 >> 32) != want)
            p2 = __hip_atomic_load(&sbuf[tid + 1024], __ATOMIC_RELAXED, __HIP_MEMORY_SCOPE_AGENT);
        if ((unsigned)(p3 >> 32) != want)
            p3 = __hip_atomic_load(&sbuf[tid + 1536], __ATOMIC_RELAXED, __HIP_MEMORY_SCOPE_AGENT);

        sl[tid]        = __uint_as_float((unsigned)p0);
        sl[tid +  512] = __uint_as_float((unsigned)p1);
        __syncthreads();

        // prefetch next step's externals (HBM latency hides under compute)
        if (t + 1 < TT) {
            inp_c = inputs[(t + 1) * NIN + lane];
            po_c  = (lane < NOUT) ? outputs[t * NOUT + lane] : 0.0f;
            nz_c  = (lane < 2) ? noise[(size_t)(t + 1) * NRES + row0 + lane] : 0.0f;
        }

        // ---- chunk-0 FMAs (j = 0..3), overlapped with chunk-1 observe ----
        const float4* s4 = (const float4*)sl;
#pragma unroll
        for (int j = 0; j < 4; ++j) {
            float4 sv = s4[64 * j + lane];
            a0 = fmaf(wv0[j].x, sv.x, a0); a0 = fmaf(wv0[j].y, sv.y, a0);
            a0 = fmaf(wv0[j].z, sv.z, a0); a0 = fmaf(wv0[j].w, sv.w, a0);
            a1 = fmaf(wv1[j].x, sv.x, a1); a1 = fmaf(wv1[j].y, sv.y, a1);
            a1 = fmaf(wv1[j].z, sv.z, a1); a1 = fmaf(wv1[j].w, sv.w, a1);
        }

        // ---- chunk-1 gate (rows 1024..2047) ----
        while ((unsigned)(p2 >> 32) != want)
            p2 = __hip_atomic_load(&sbuf[tid + 1024], __ATOMIC_RELAXED, __HIP_MEMORY_SCOPE_AGENT);
        while ((unsigned)(p3 >> 32) != want)
            p3 = __hip_atomic_load(&sbuf[tid + 1536], __ATOMIC_RELAXED, __HIP_MEMORY_SCOPE_AGENT);
        sl[tid + 1024] = __uint_as_float((unsigned)p2);
        sl[tid + 1536] = __uint_as_float((unsigned)p3);
        __syncthreads();

        // ---- chunk-1 FMAs (j = 4..7) ----
#pragma unroll
        for (int j = 4; j < NJ; ++j) {
            float4 sv = s4[64 * j + lane];
            a0 = fmaf(wv0[j].x, sv.x, a0); a0 = fmaf(wv0[j].y, sv.y, a0);
            a0 = fmaf(wv0[j].z, sv.z, a0); a0 = fmaf(wv0[j].w, sv.w, a0);
            a1 = fmaf(wv1[j].x, sv.x, a1); a1 = fmaf(wv1[j].y, sv.y, a1);
            a1 = fmaf(wv1[j].z, sv.z, a1); a1 = fmaf(wv1[j].w, sv.w, a1);
        }

        // ---- paired reduction: 6 shuffles for both rows ----
        float c = (lane & 1) ? a1 : a0;
        float d = (lane & 1) ? a0 : a1;
        c += __shfl_xor(d, 1, 64);
#pragma unroll
        for (int off = 2; off <= 32; off <<= 1) c += __shfl_xor(c, off, 64);
        // lane 0: full a0 sum; lane 1: full a1 sum

        float ns = tanhf(c) + nz;      // all lanes compute; only 0,1 used
        if (lane < 2) {
            u64 pk = ((u64)(unsigned)t << 32) | (u64)__float_as_uint(ns);
            __hip_atomic_store(&dbuf[row0 + lane], pk, __ATOMIC_RELAXED,
                               __HIP_MEMORY_SCOPE_AGENT);
        }
    }
}

__global__ void epilogue(const u64* __restrict__ statebuf,
                         const float* __restrict__ inputs,
                         const float* __restrict__ outputs,
                         const float* __restrict__ w_out,
                         float* __restrict__ out)
{
    const u64* sb = statebuf + ((TT - 1) & 1) * NRES;   // state(4095) in buf 1
    const int tid  = threadIdx.x;   // 1024 threads = 16 waves
    const int wave = tid >> 6;
    const int lane = tid & 63;

    float acc = 0.0f;
#pragma unroll
    for (int k = 0; k < NRES / 64; ++k) {
        int r = lane + 64 * k;
        acc = fmaf(__uint_as_float((unsigned)sb[r]), w_out[r * NOUT + wave], acc);
    }
#pragma unroll
    for (int off = 32; off; off >>= 1) acc += __shfl_xor(acc, off, 64);
    if (lane == 0) out[wave] = acc;

    for (int i = tid; i < NRES; i += 1024)
        out[NOUT + i] = __uint_as_float((unsigned)sb[i]);
    if (tid < NIN)  out[NOUT + NRES + tid]       = inputs[(TT - 1) * NIN + tid];
    if (tid < NOUT) out[NOUT + NRES + NIN + tid] = outputs[(TT - 2) * NOUT + tid];
}

extern "C" void kernel_launch(void* const* d_in, const int* in_sizes, int n_in,
                              void* d_out, int out_size, void* d_ws, size_t ws_size,
                              hipStream_t stream) {
    const float* inputs  = (const float*)d_in[0];   // (4096, 64)
    const float* outputs = (const float*)d_in[1];   // (4096, 16)
    const float* noise   = (const float*)d_in[2];   // (4096, 2048)
    const float* w       = (const float*)d_in[3];   // (2048, 2048)
    const float* w_in    = (const float*)d_in[4];   // (2048, 64)
    const float* w_feedb = (const float*)d_in[5];   // (2048, 16)
    const float* w_out   = (const float*)d_in[6];   // (2048, 16)
    float* out = (float*)d_out;                     // 16 + 2128 floats

    u64* statebuf = (u64*)d_ws;                     // 2 * 2048 u64 = 32 KB

    init_ws<<<dim3(8), dim3(512), 0, stream>>>(statebuf);
    reservoir_run<<<dim3(GWG), dim3(BTH), 0, stream>>>(inputs, outputs, noise,
                                                       w, w_in, w_feedb, statebuf);
    epilogue<<<dim3(1), dim3(1024), 0, stream>>>(statebuf, inputs, outputs, w_out, out);
}

// Round 8
// 10769.994 us; speedup vs baseline: 1.2874x; 1.2874x over previous
//
#include <hip/hip_runtime.h>

// Reservoir forward, R8 = R6 + 16-way replicated publish.
//   Epoch-tagged u64 state exchange via relaxed agent-scope atomics (IF-resolved).
//   NEW: publishers store each state word into 16 replica buffers (lanes 0..31,
//   replica = lane>>1); consumer wg polls replica (wg & 15) only. This cuts the
//   per-cache-line poll flood 16x, attacking IF congestion (R6's residual ~1us).
//   R7 lesson: no extra gates -- one poll burst, one barrier, then compute.

typedef unsigned long long u64;

#define NRES 2048
#define NIN  64
#define NOUT 16
#define TT   4096
#define GWG  128           // workgroups
#define BTH  512           // threads per wg (8 waves)
#define ROWS_PER_WG 16     // NRES / GWG, 2 rows per wave
#define NJ 8               // float4 blocks per lane (32 cols)
#define NREP 16            // publish replicas

__global__ void init_ws(u64* statebuf) {
    int i = blockIdx.x * blockDim.x + threadIdx.x;   // 65536 threads
    if (i < NREP * NRES)            statebuf[i] = 0ull;                   // par0: epoch 0, val 0
    else if (i < 2 * NREP * NRES)   statebuf[i] = 0xFFFFFFFF00000000ull;  // par1: invalid
}

__launch_bounds__(BTH, 2)   // VGPR cap 256; W (64 regs) fits
__global__ void reservoir_run(const float* __restrict__ inputs,
                              const float* __restrict__ outputs,
                              const float* __restrict__ noise,
                              const float* __restrict__ w,
                              const float* __restrict__ w_in,
                              const float* __restrict__ w_feedb,
                              u64* statebuf)
{
    const int wg   = blockIdx.x;      // 0..127
    const int tid  = threadIdx.x;     // 0..511
    const int wave = tid >> 6;        // 0..7
    const int lane = tid & 63;
    const int row0 = wg * ROWS_PER_WG + wave * 2;   // wave owns rows row0, row0+1
    const int myrep = wg & (NREP - 1);              // replica this wg polls

    // ---- W rows into VGPRs: 2 rows x 8 float4 = 64 regs/thread ----
    const float4* wr0 = (const float4*)(w + (size_t)(row0 + 0) * NRES);
    const float4* wr1 = (const float4*)(w + (size_t)(row0 + 1) * NRES);
    float4 wv0[NJ], wv1[NJ];
#pragma unroll
    for (int j = 0; j < NJ; ++j) {
        wv0[j] = wr0[64 * j + lane];
        wv1[j] = wr1[64 * j + lane];
    }
    // pin: block rematerialization (R3's failure mode)
#pragma unroll
    for (int j = 0; j < NJ; ++j) {
        asm volatile("" : "+v"(wv0[j].x), "+v"(wv0[j].y), "+v"(wv0[j].z), "+v"(wv0[j].w));
        asm volatile("" : "+v"(wv1[j].x), "+v"(wv1[j].y), "+v"(wv1[j].z), "+v"(wv1[j].w));
    }
    const float wi0 = w_in[(row0 + 0) * NIN + lane];
    const float wi1 = w_in[(row0 + 1) * NIN + lane];
    const float wf0 = (lane < NOUT) ? w_feedb[(row0 + 0) * NOUT + lane] : 0.0f;
    const float wf1 = (lane < NOUT) ? w_feedb[(row0 + 1) * NOUT + lane] : 0.0f;

    __shared__ float s_state[2][NRES];   // 16 KB parity double buffer

    // software-pipelined externals.
    // nz: lanes 0..31 carry noise for row0+(lane&1) -- all publisher lanes need it.
    float inp_c = inputs[1 * NIN + lane];
    float po_c  = (lane < NOUT) ? outputs[0 * NOUT + lane] : 0.0f;
    float nz_c  = (lane < 32) ? noise[(size_t)1 * NRES + row0 + (lane & 1)] : 0.0f;

    for (int t = 1; t < TT; ++t) {
        const u64* sbuf = statebuf + ((size_t)((t - 1) & 1)) * NREP * NRES
                                   + (size_t)myrep * NRES;
        u64*       dbuf = statebuf + ((size_t)(t & 1)) * NREP * NRES;
        float*     sl   = s_state[(t - 1) & 1];
        const unsigned want = (unsigned)(t - 1);

        float a0 = fmaf(wf0, po_c, wi0 * inp_c);
        float a1 = fmaf(wf1, po_c, wi1 * inp_c);
        const float nz = nz_c;

        // ---- poll-stage state(t-1) from this wg's replica: 4 u64, in flight ----
        u64 p0 = __hip_atomic_load(&sbuf[tid],        __ATOMIC_RELAXED, __HIP_MEMORY_SCOPE_AGENT);
        u64 p1 = __hip_atomic_load(&sbuf[tid +  512], __ATOMIC_RELAXED, __HIP_MEMORY_SCOPE_AGENT);
        u64 p2 = __hip_atomic_load(&sbuf[tid + 1024], __ATOMIC_RELAXED, __HIP_MEMORY_SCOPE_AGENT);
        u64 p3 = __hip_atomic_load(&sbuf[tid + 1536], __ATOMIC_RELAXED, __HIP_MEMORY_SCOPE_AGENT);
        while ((unsigned)(p0 >> 32) != want)
            p0 = __hip_atomic_load(&sbuf[tid],        __ATOMIC_RELAXED, __HIP_MEMORY_SCOPE_AGENT);
        while ((unsigned)(p1 >> 32) != want)
            p1 = __hip_atomic_load(&sbuf[tid +  512], __ATOMIC_RELAXED, __HIP_MEMORY_SCOPE_AGENT);
        while ((unsigned)(p2 >> 32) != want)
            p2 = __hip_atomic_load(&sbuf[tid + 1024], __ATOMIC_RELAXED, __HIP_MEMORY_SCOPE_AGENT);
        while ((unsigned)(p3 >> 32) != want)
            p3 = __hip_atomic_load(&sbuf[tid + 1536], __ATOMIC_RELAXED, __HIP_MEMORY_SCOPE_AGENT);
        sl[tid]        = __uint_as_float((unsigned)p0);
        sl[tid +  512] = __uint_as_float((unsigned)p1);
        sl[tid + 1024] = __uint_as_float((unsigned)p2);
        sl[tid + 1536] = __uint_as_float((unsigned)p3);
        __syncthreads();

        // prefetch next step's externals (hide under FMA phase)
        if (t + 1 < TT) {
            inp_c = inputs[(t + 1) * NIN + lane];
            po_c  = (lane < NOUT) ? outputs[t * NOUT + lane] : 0.0f;
            nz_c  = (lane < 32) ? noise[(size_t)(t + 1) * NRES + row0 + (lane & 1)] : 0.0f;
        }

        // ---- 2 row dot-products, float4 LDS reads (ds_read_b128) ----
        const float4* s4 = (const float4*)sl;
#pragma unroll
        for (int j = 0; j < NJ; ++j) {
            float4 sv = s4[64 * j + lane];
            a0 = fmaf(wv0[j].x, sv.x, a0); a0 = fmaf(wv0[j].y, sv.y, a0);
            a0 = fmaf(wv0[j].z, sv.z, a0); a0 = fmaf(wv0[j].w, sv.w, a0);
            a1 = fmaf(wv1[j].x, sv.x, a1); a1 = fmaf(wv1[j].y, sv.y, a1);
            a1 = fmaf(wv1[j].z, sv.z, a1); a1 = fmaf(wv1[j].w, sv.w, a1);
        }

        // ---- paired reduction: 6 shuffles; even lanes end with full a0 sum,
        //      odd lanes with full a1 sum (xor-class property) ----
        float c = (lane & 1) ? a1 : a0;
        float d = (lane & 1) ? a0 : a1;
        c += __shfl_xor(d, 1, 64);
#pragma unroll
        for (int off = 2; off <= 32; off <<= 1) c += __shfl_xor(c, off, 64);

        // ---- publish to all 16 replicas: lanes 0..31, replica = lane>>1 ----
        float ns = tanhf(c) + nz;      // valid on lanes 0..31 (nz per lane&1)
        if (lane < 2 * NREP) {
            int rep = lane >> 1;
            u64 pk = ((u64)(unsigned)t << 32) | (u64)__float_as_uint(ns);
            __hip_atomic_store(&dbuf[(size_t)rep * NRES + row0 + (lane & 1)], pk,
                               __ATOMIC_RELAXED, __HIP_MEMORY_SCOPE_AGENT);
        }
    }
}

__global__ void epilogue(const u64* __restrict__ statebuf,
                         const float* __restrict__ inputs,
                         const float* __restrict__ outputs,
                         const float* __restrict__ w_out,
                         float* __restrict__ out)
{
    // state(4095) lives in parity 1, replica 0
    const u64* sb = statebuf + (size_t)((TT - 1) & 1) * NREP * NRES;
    const int tid  = threadIdx.x;   // 1024 threads = 16 waves
    const int wave = tid >> 6;
    const int lane = tid & 63;

    float acc = 0.0f;
#pragma unroll
    for (int k = 0; k < NRES / 64; ++k) {
        int r = lane + 64 * k;
        acc = fmaf(__uint_as_float((unsigned)sb[r]), w_out[r * NOUT + wave], acc);
    }
#pragma unroll
    for (int off = 32; off; off >>= 1) acc += __shfl_xor(acc, off, 64);
    if (lane == 0) out[wave] = acc;

    for (int i = tid; i < NRES; i += 1024)
        out[NOUT + i] = __uint_as_float((unsigned)sb[i]);
    if (tid < NIN)  out[NOUT + NRES + tid]       = inputs[(TT - 1) * NIN + tid];
    if (tid < NOUT) out[NOUT + NRES + NIN + tid] = outputs[(TT - 2) * NOUT + tid];
}

extern "C" void kernel_launch(void* const* d_in, const int* in_sizes, int n_in,
                              void* d_out, int out_size, void* d_ws, size_t ws_size,
                              hipStream_t stream) {
    const float* inputs  = (const float*)d_in[0];   // (4096, 64)
    const float* outputs = (const float*)d_in[1];   // (4096, 16)
    const float* noise   = (const float*)d_in[2];   // (4096, 2048)
    const float* w       = (const float*)d_in[3];   // (2048, 2048)
    const float* w_in    = (const float*)d_in[4];   // (2048, 64)
    const float* w_feedb = (const float*)d_in[5];   // (2048, 16)
    const float* w_out   = (const float*)d_in[6];   // (2048, 16)
    float* out = (float*)d_out;                     // 16 + 2128 floats

    u64* statebuf = (u64*)d_ws;                     // 2 * 16 * 2048 u64 = 512 KB

    init_ws<<<dim3(128), dim3(512), 0, stream>>>(statebuf);
    reservoir_run<<<dim3(GWG), dim3(BTH), 0, stream>>>(inputs, outputs, noise,
                                                       w, w_in, w_feedb, statebuf);
    epilogue<<<dim3(1), dim3(1024), 0, stream>>>(statebuf, inputs, outputs, w_out, out);
}